// Round 1
// baseline (52.725 us; speedup 1.0000x reference)
//
#include <hip/hip_runtime.h>
#include <stdint.h>

// FlagBagEncoder: out[t,:] = mean over {k : flags[t,k] > 0.5} of W[k,:], zeros if empty.
// T=100000, K=512, D=64, fp32 in/out.
//
// Strategy: bf16 MFMA (mask is exact in bf16; W bf16 rounding error ~3e-4 << 6.3e-3 thr).
// One wave per 16-row tile, mfma_f32_16x16x32_bf16, 4 n-tiles (D=64), 16 K-steps.
// B-fragments (bf16 W) precomputed by a prep kernel into a 64KB device-global scratch,
// read as coalesced L2-resident dwordx4 in the main loop. Flags loaded directly from
// global as float4 (full 128B-per-row-per-step line utilization). 1-step prefetch.

#define T_ROWS 100000
#define K_FLAGS 512
#define D_DIM 64
#define TILES (T_ROWS / 16)   // 6250, exact

typedef __attribute__((ext_vector_type(4))) float f32x4;
typedef __attribute__((ext_vector_type(8))) short bf16x8;

// 16 k-steps x 4 n-tiles x 64 lanes x 4 dwords = 64 KB of prepacked B fragments.
__device__ uint32_t g_bfrag[16 * 4 * 64 * 4];

__device__ __forceinline__ uint32_t f32_to_bf16_rne(float f) {
  union { float f; uint32_t u; } v; v.f = f;
  uint32_t u = v.u;
  return (u + 0x7FFFu + ((u >> 16) & 1u)) >> 16;
}

// Fragment mapping (symmetric for A and B, so any within-group k-permutation cancels):
// lane l, element e (0..7): k = (l>>4)*8 + 32*s + e ; A row m = l&15 ; B col n = (l&15)+16*nt.
// Packed dword j of the fragment holds elements (2j, 2j+1) as (lo, hi) bf16.
__global__ void prep_b_kernel(const float* __restrict__ W) {
  int tid = blockIdx.x * blockDim.x + threadIdx.x;
  if (tid >= 16 * 4 * 64) return;
  int lane = tid & 63;
  int nt   = (tid >> 6) & 3;
  int s    = tid >> 8;
  int n    = (lane & 15) + 16 * nt;
  int kb   = (lane >> 4) * 8 + 32 * s;
  uint32_t r[4];
#pragma unroll
  for (int j = 0; j < 4; ++j) {
    uint32_t lo = f32_to_bf16_rne(W[(size_t)(kb + 2 * j    ) * D_DIM + n]);
    uint32_t hi = f32_to_bf16_rne(W[(size_t)(kb + 2 * j + 1) * D_DIM + n]);
    r[j] = lo | (hi << 16);
  }
  *reinterpret_cast<uint4*>(&g_bfrag[(size_t)tid * 4]) = make_uint4(r[0], r[1], r[2], r[3]);
}

__global__ __launch_bounds__(256) void flagbag_kernel(const float* __restrict__ flags,
                                                      float* __restrict__ out) {
  const int lane = threadIdx.x & 63;
  const int wave = threadIdx.x >> 6;
  const int tile = blockIdx.x * 4 + wave;
  if (tile >= TILES) return;

  const int t0 = tile * 16;
  const int m  = lane & 15;   // A row within tile / output col within n-tile
  const int kq = lane >> 4;   // k quarter-group

  const float* frow = flags + (size_t)(t0 + m) * K_FLAGS + kq * 8;
  const uint4* bbase = reinterpret_cast<const uint4*>(g_bfrag) + lane;

  f32x4 acc[4];
#pragma unroll
  for (int nt = 0; nt < 4; ++nt) acc[nt] = (f32x4){0.f, 0.f, 0.f, 0.f};
  int cnt = 0;

  // prologue loads (s=0)
  f32x4 fa = *reinterpret_cast<const f32x4*>(frow);
  f32x4 fb = *reinterpret_cast<const f32x4*>(frow + 4);
  uint4 bc[4];
#pragma unroll
  for (int nt = 0; nt < 4; ++nt) bc[nt] = bbase[nt * 64];

#pragma unroll
  for (int s = 0; s < 16; ++s) {
    // prefetch next step (s=15 reloads current; dead, compiler may drop)
    const int sn = (s < 15) ? s + 1 : 15;
    f32x4 na = *reinterpret_cast<const f32x4*>(frow + 32 * sn);
    f32x4 nb = *reinterpret_cast<const f32x4*>(frow + 32 * sn + 4);
    uint4 bn[4];
#pragma unroll
    for (int nt = 0; nt < 4; ++nt) bn[nt] = bbase[(sn * 4 + nt) * 64];

    // build A fragment: bf16 mask (1.0 = 0x3F80), and exact integer count
    bf16x8 af;
#pragma unroll
    for (int j = 0; j < 4; ++j) {
      const bool sa = fa[j] > 0.5f;
      const bool sb = fb[j] > 0.5f;
      af[j]     = sa ? (short)0x3F80 : (short)0;
      af[j + 4] = sb ? (short)0x3F80 : (short)0;
      cnt += sa ? 1 : 0;
      cnt += sb ? 1 : 0;
    }

#pragma unroll
    for (int nt = 0; nt < 4; ++nt)
      acc[nt] = __builtin_amdgcn_mfma_f32_16x16x32_bf16(
          af, *reinterpret_cast<const bf16x8*>(&bc[nt]), acc[nt], 0, 0, 0);

    fa = na; fb = nb;
#pragma unroll
    for (int nt = 0; nt < 4; ++nt) bc[nt] = bn[nt];
  }

  // full row count: lanes {m, m+16, m+32, m+48} each hold 128 of the 512 k's
  cnt += __shfl_xor(cnt, 16);
  cnt += __shfl_xor(cnt, 32);
  const float inv = (cnt > 0) ? (1.0f / (float)cnt) : 0.0f;

  // C/D layout (HW-verified): col = lane&15, row = (lane>>4)*4 + reg
#pragma unroll
  for (int r = 0; r < 4; ++r) {
    const int row = kq * 4 + r;
    const float invr = __shfl(inv, row);  // lane 'row' holds count for row 'row'
    float* orow = out + (size_t)(t0 + row) * D_DIM + m;
#pragma unroll
    for (int nt = 0; nt < 4; ++nt)
      orow[16 * nt] = acc[nt][r] * invr;
  }
}

extern "C" void kernel_launch(void* const* d_in, const int* in_sizes, int n_in,
                              void* d_out, int out_size, void* d_ws, size_t ws_size,
                              hipStream_t stream) {
  const float* flags = (const float*)d_in[0];
  const float* W     = (const float*)d_in[1];
  float* out         = (float*)d_out;

  hipLaunchKernelGGL(prep_b_kernel, dim3(16), dim3(256), 0, stream, W);

  const int blocks = (TILES + 3) / 4;  // 4 waves/block, 1 tile/wave
  hipLaunchKernelGGL(flagbag_kernel, dim3(blocks), dim3(256), 0, stream, flags, out);
}